// Round 6
// baseline (4734.461 us; speedup 1.0000x reference)
//
#include <hip/hip_runtime.h>
#include <hip/hip_bf16.h>
#include <math.h>

#define Bz   64
#define Sz   512
#define DIN  1024
#define DH   2048
#define DOUT 1024
#define FUT  16
#define KTOT (DIN + DH)   // 3072

#define SENT 0x80008000u   // bf16 pair (-0.0,-0.0); producers never emit it

typedef __attribute__((ext_vector_type(8))) __bf16 bf16x8;
typedef __attribute__((ext_vector_type(4))) float  f32x4;

union U16x8 { uint4 u; bf16x8 v; };

__device__ __forceinline__ uint4 pack_bf8(float4 a, float4 b) {
  bf16x8 t;
  t[0]=(__bf16)a.x; t[1]=(__bf16)a.y; t[2]=(__bf16)a.z; t[3]=(__bf16)a.w;
  t[4]=(__bf16)b.x; t[5]=(__bf16)b.y; t[6]=(__bf16)b.z; t[7]=(__bf16)b.w;
  U16x8 u; u.v = t; return u.u;
}

// branch-free tanh: 1 - 2/(e^{2x}+1), e^{2x}=2^(2*log2e*x). Saturates to ±1.
__device__ __forceinline__ float fast_tanh(float x) {
  const float e = __builtin_amdgcn_exp2f(2.8853900817779268f * x);
  return 1.0f - 2.0f * __builtin_amdgcn_rcpf(e + 1.0f);
}

// ---------------------------------------------------------------------------
// 64x64-tile GEMM core (unchanged; used by xw/out/future kernels)
// ---------------------------------------------------------------------------
template<bool AF32>
__device__ __forceinline__ void gemm_core(
    const void* __restrict__ Abase, size_t astride,
    const __bf16* __restrict__ Bbase, size_t bstride,
    int K, f32x4 acc[2][2])
{
  __shared__ uint4 Al[2][512];
  __shared__ uint4 Bl[2][512];

  const int tid  = threadIdx.x;
  const int lane = tid & 63;
  const int wave = tid >> 6;
  const int wm = (wave >> 1) << 5;
  const int wn = (wave & 1) << 5;
  const int fr = lane & 15;
  const int fg = lane >> 4;

  const int srow = tid >> 2;
  const int sck  = (tid & 3) << 1;

  const int NK = K >> 6;
  if (NK <= 0) return;

  uint4 ra0, ra1, rb0, rb1;

  auto loadt = [&](int kt) {
    const int kelt = (kt << 6) + (sck << 3);
    if constexpr (AF32) {
      const float* ap = (const float*)Abase + (size_t)srow * astride + kelt;
      float4 a0 = *(const float4*)(ap);
      float4 a1 = *(const float4*)(ap + 4);
      float4 a2 = *(const float4*)(ap + 8);
      float4 a3 = *(const float4*)(ap + 12);
      ra0 = pack_bf8(a0, a1);
      ra1 = pack_bf8(a2, a3);
    } else {
      const __bf16* ap = (const __bf16*)Abase + (size_t)srow * astride + kelt;
      ra0 = *(const uint4*)(ap);
      ra1 = *(const uint4*)(ap + 8);
    }
    const __bf16* bp = Bbase + (size_t)srow * bstride + kelt;
    rb0 = *(const uint4*)(bp);
    rb1 = *(const uint4*)(bp + 8);
  };

  auto storet = [&](int buf) {
    const int x7 = srow & 7;
    Al[buf][srow * 8 + ( sck      ^ x7)] = ra0;
    Al[buf][srow * 8 + ((sck + 1) ^ x7)] = ra1;
    Bl[buf][srow * 8 + ( sck      ^ x7)] = rb0;
    Bl[buf][srow * 8 + ((sck + 1) ^ x7)] = rb1;
  };

  loadt(0);
  storet(0);
  __syncthreads();

  for (int kt = 0; kt < NK; ++kt) {
    const int  cur  = kt & 1;
    const bool more = (kt + 1) < NK;
    if (more) loadt(kt + 1);

    #pragma unroll
    for (int kk = 0; kk < 2; ++kk) {
      bf16x8 af[2], bfrag[2];
      #pragma unroll
      for (int mi = 0; mi < 2; ++mi) {
        const int row = wm + mi * 16 + fr;
        const int ck  = (kk * 4 + fg) ^ (row & 7);
        U16x8 u; u.u = Al[cur][row * 8 + ck]; af[mi] = u.v;
      }
      #pragma unroll
      for (int ni = 0; ni < 2; ++ni) {
        const int row = wn + ni * 16 + fr;
        const int ck  = (kk * 4 + fg) ^ (row & 7);
        U16x8 u; u.u = Bl[cur][row * 8 + ck]; bfrag[ni] = u.v;
      }
      #pragma unroll
      for (int mi = 0; mi < 2; ++mi)
        #pragma unroll
        for (int ni = 0; ni < 2; ++ni)
          acc[mi][ni] = __builtin_amdgcn_mfma_f32_16x16x32_bf16(
              af[mi], bfrag[ni], acc[mi][ni], 0, 0, 0);
    }

    __syncthreads();
    if (more) storet((kt + 1) & 1);
    __syncthreads();
  }
}

#define EPI_SETUP() \
  const int tid = threadIdx.x, lane = tid & 63, wave = tid >> 6; \
  const int wm = (wave >> 1) << 5, wn = (wave & 1) << 5; \
  const int fr = lane & 15, fg = lane >> 4;

// ---------------------------------------------------------------------------
__global__ __launch_bounds__(256) void k_transp(const float* __restrict__ W,
                                                __bf16* __restrict__ WT,
                                                int K, int N)
{
  __shared__ float T[64][65];
  const int k0 = blockIdx.x << 6, n0 = blockIdx.y << 6;
  const int c = threadIdx.x & 63, r4 = threadIdx.x >> 6;
  #pragma unroll
  for (int rr = 0; rr < 16; ++rr) {
    const int r = rr * 4 + r4;
    T[r][c] = W[(size_t)(k0 + r) * N + n0 + c];
  }
  __syncthreads();
  #pragma unroll
  for (int rr = 0; rr < 16; ++rr) {
    const int r = rr * 4 + r4;
    WT[(size_t)(n0 + r) * K + k0 + c] = (__bf16)T[c][r];
  }
}

// ---------------------------------------------------------------------------
// Sentinel fill for the h ring buffer
// ---------------------------------------------------------------------------
__global__ __launch_bounds__(256) void k_sent(uint4* __restrict__ p, int n4)
{
  const uint4 s = { SENT, SENT, SENT, SENT };
  for (int i = blockIdx.x * 256 + threadIdx.x; i < n4; i += gridDim.x * 256)
    p[i] = s;
}

// ---------------------------------------------------------------------------
// Phase A: HX[s][b][n] = bf16( x[b][s][:] . Wx[:,n] + bh[n] )   (pre-tanh)
// ---------------------------------------------------------------------------
__global__ __launch_bounds__(256) void k_gemm_xw(const float* __restrict__ x,
                                                 const __bf16* __restrict__ WhT,
                                                 const float* __restrict__ bh,
                                                 __bf16* __restrict__ HX)
{
  const int s = blockIdx.x;
  const int n0 = blockIdx.y << 6;
  f32x4 acc[2][2] = {};
  gemm_core<true>(x + (size_t)s * DIN, (size_t)Sz * DIN,
                  WhT + (size_t)n0 * KTOT, KTOT, DIN, acc);
  EPI_SETUP();
  __bf16* out = HX + (size_t)s * Bz * DH;
  #pragma unroll
  for (int mi = 0; mi < 2; ++mi)
    #pragma unroll
    for (int ni = 0; ni < 2; ++ni)
      #pragma unroll
      for (int r = 0; r < 4; ++r) {
        const int m = wm + mi * 16 + fg * 4 + r;
        const int n = n0 + wn + ni * 16 + fr;
        out[(size_t)m * DH + n] = (__bf16)(acc[mi][ni][r] + bh[n]);
      }
}

// ---------------------------------------------------------------------------
// Persistent RNN recurrence. r5 -> r6: SENTINEL-POLLED DATA RING, no flags.
//   Hbuf[8][Bz][DH] pre-filled with SENT. Producers store h (sc0sc1, nudged
//   so the SENT dword never occurs) to slot t&7 with NO ack wait and NO flag;
//   consumers poll-load their A-tile (sc0sc1) until all dwords != SENT — the
//   detecting load IS the data. Producer re-sentinels slot (t+4)&7 (its own
//   tile bytes) off the critical path; safe since cross-block drift <= 1.
//   XW (HX) is read-only here -> plain cached prefetch. h also persisted to
//   HX[t] (sc0sc1 dword stores; no L2 line ownership -> no false sharing)
//   for k_out / k_finit.
// ---------------------------------------------------------------------------
#define RNN_SMEM (131072 + 8192)

__global__ __launch_bounds__(256) void k_rnn(const __bf16* __restrict__ WhT,
                                             __bf16* __restrict__ HX,
                                             __bf16* __restrict__ Hbuf)
{
  extern __shared__ char smem[];
  uint4* WT  = (uint4*)smem;              // [32][256] uint4, swizzled
  float* RED = (float*)(smem + 131072);   // [4][2][16][16] f32

  const int mb   = blockIdx.x & 3;
  const int nb   = blockIdx.x >> 2;
  const int tid  = threadIdx.x;
  const int lane = tid & 63;
  const int wave = tid >> 6;        // k-quarter owner
  const int fr   = lane & 15;
  const int fg   = lane >> 4;

  // ---- stage Whh slice into LDS (once) ----
  for (int i = tid; i < 32 * 256; i += 256) {
    const int n = i >> 8, c = i & 255;
    uint4 v = *(const uint4*)(WhT + (size_t)(nb * 32 + n) * KTOT + DIN + c * 8);
    WT[(n << 8) | (c ^ (n & 7))] = v;
  }
  __syncthreads();

  // ---- per-thread output mapping (reduce phase) ----
  const int tt   = tid >> 7;        // n-subtile 0/1
  const int row  = (tid >> 3) & 15; // tile row
  const int cpp  = tid & 7;         // col pair
  const int grow = mb * 16 + row;
  const int gcol = nb * 32 + tt * 16 + cpp * 2;

  for (int t = 0; t < Sz; ++t) {
    __bf16* Hc = HX + (size_t)t * Bz * DH;

    // XW prefetch: HX is read-only in this kernel -> plain cached load,
    // in flight during the poll below.
    const unsigned int xwp = *(const unsigned int*)(Hc + (size_t)grow * DH + gcol);

    f32x4 acc[2] = {};

    if (t > 0) {
      const __bf16* Hp = Hbuf + (size_t)((t - 1) & 7) * Bz * DH
                       + (size_t)(mb * 16 + fr) * DH + (wave << 9) + (fg << 3);
      uint4 areg[16];
      for (;;) {
        #pragma unroll
        for (int kk = 0; kk < 16; ++kk) {
          asm volatile("global_load_dwordx4 %0, %1, off sc0 sc1"
                       : "=v"(areg[kk])
                       : "v"((const void*)(Hp + kk * 32))
                       : "memory");
        }
        asm volatile("s_waitcnt vmcnt(0)" ::: "memory");
        __builtin_amdgcn_sched_barrier(0);
        bool ok = true;
        #pragma unroll
        for (int kk = 0; kk < 16; ++kk) {
          ok &= (areg[kk].x != SENT) & (areg[kk].y != SENT)
              & (areg[kk].z != SENT) & (areg[kk].w != SENT);
        }
        if (__all((int)ok)) break;
        __builtin_amdgcn_s_sleep(1);
      }

      #pragma unroll
      for (int kk = 0; kk < 16; ++kk) {
        U16x8 ua; ua.u = areg[kk];
        const int c = (wave << 6) + (kk << 2) + fg;
        U16x8 w0, w1;
        w0.u = WT[(fr << 8)        | (c ^ (fr & 7))];
        w1.u = WT[((16 + fr) << 8) | (c ^ (fr & 7))];
        acc[0] = __builtin_amdgcn_mfma_f32_16x16x32_bf16(ua.v, w0.v, acc[0], 0, 0, 0);
        acc[1] = __builtin_amdgcn_mfma_f32_16x16x32_bf16(ua.v, w1.v, acc[1], 0, 0, 0);
      }
    }

    // ---- cross-wave K reduction through LDS ----
    #pragma unroll
    for (int t2 = 0; t2 < 2; ++t2)
      #pragma unroll
      for (int r = 0; r < 4; ++r)
        RED[((wave * 2 + t2) << 8) + (fg * 4 + r) * 16 + fr] = acc[t2][r];
    __syncthreads();

    const float2* rp = (const float2*)RED;
    float2 s = {0.f, 0.f};
    #pragma unroll
    for (int w = 0; w < 4; ++w) {
      const float2 v = rp[((w * 2 + tt) << 7) + (row << 3) + cpp];
      s.x += v.x; s.y += v.y;
    }

    union { unsigned int u; __bf16 h[2]; } ux; ux.u = xwp;
    const float z0 = s.x + (float)ux.h[0];
    const float z1 = s.y + (float)ux.h[1];
    union { unsigned int u; __bf16 h[2]; } po;
    po.h[0] = (__bf16)fast_tanh(z0);
    po.h[1] = (__bf16)fast_tanh(z1);
    if (po.u == SENT) po.u = 0x80000000u;   // (-0,-0) -> (-0,+0): same value

    // 1) consumer-visible h store (ring slot t&7) — fire and forget
    __bf16* hb = Hbuf + (size_t)(t & 7) * Bz * DH + (size_t)grow * DH + gcol;
    asm volatile("global_store_dword %0, %1, off sc0 sc1"
                 :: "v"((void*)hb), "v"(po.u) : "memory");
    // 2) persistence store for k_out/k_finit (dword-granular, no L2 line own)
    asm volatile("global_store_dword %0, %1, off sc0 sc1"
                 :: "v"((void*)(Hc + (size_t)grow * DH + gcol)), "v"(po.u)
                 : "memory");
    // 3) re-sentinel slot (t+4)&7 (holds h(t-4); all readers long done)
    __bf16* cs = Hbuf + (size_t)((t + 4) & 7) * Bz * DH + (size_t)grow * DH + gcol;
    asm volatile("global_store_dword %0, %1, off sc0 sc1"
                 :: "v"((void*)cs), "v"(SENT) : "memory");

    __syncthreads();   // RED WAR barrier (next iteration rewrites RED)
  }
}

// ---------------------------------------------------------------------------
// Phase C: out[b][s][n] = HX[s][b][:] . Wo[:,n] + bo[n]
// ---------------------------------------------------------------------------
__global__ __launch_bounds__(256) void k_out(const __bf16* __restrict__ HX,
                                             const __bf16* __restrict__ WoT,
                                             const float* __restrict__ bo,
                                             float* __restrict__ out)
{
  const int s = blockIdx.x;
  const int n0 = blockIdx.y << 6;
  f32x4 acc[2][2] = {};
  gemm_core<false>(HX + (size_t)s * Bz * DH, DH,
                   WoT + (size_t)n0 * DH, DH, DH, acc);
  EPI_SETUP();
  #pragma unroll
  for (int mi = 0; mi < 2; ++mi)
    #pragma unroll
    for (int ni = 0; ni < 2; ++ni)
      #pragma unroll
      for (int r = 0; r < 4; ++r) {
        const int m = wm + mi * 16 + fg * 4 + r;
        const int n = n0 + wn + ni * 16 + fr;
        out[((size_t)m * Sz + s) * DOUT + n] = acc[mi][ni][r] + bo[n];
      }
}

// ---------------------------------------------------------------------------
__global__ __launch_bounds__(256) void k_finit(const float* __restrict__ x,
                                               const __bf16* __restrict__ HX,
                                               __bf16* __restrict__ zf0)
{
  const int b = blockIdx.x;
  for (int k = threadIdx.x; k < DIN; k += 256)
    zf0[(size_t)b * KTOT + k] =
        (__bf16)x[((size_t)b * Sz + (Sz - 1)) * DIN + k];
  for (int k = threadIdx.x; k < DH; k += 256)
    zf0[(size_t)b * KTOT + DIN + k] =
        HX[(size_t)(Sz - 1) * Bz * DH + (size_t)b * DH + k];
}

__global__ __launch_bounds__(256) void k_fstep(const __bf16* __restrict__ zc,
                                               __bf16* __restrict__ zn,
                                               const __bf16* __restrict__ WhT,
                                               const float* __restrict__ bh)
{
  const int n0 = blockIdx.x << 6;
  f32x4 acc[2][2] = {};
  gemm_core<false>(zc, KTOT, WhT + (size_t)n0 * KTOT, KTOT, KTOT, acc);
  EPI_SETUP();
  #pragma unroll
  for (int mi = 0; mi < 2; ++mi)
    #pragma unroll
    for (int ni = 0; ni < 2; ++ni)
      #pragma unroll
      for (int r = 0; r < 4; ++r) {
        const int m = wm + mi * 16 + fg * 4 + r;
        const int n = n0 + wn + ni * 16 + fr;
        zn[(size_t)m * KTOT + DIN + n] = (__bf16)fast_tanh(acc[mi][ni][r] + bh[n]);
      }
}

__global__ __launch_bounds__(256) void k_fout(__bf16* __restrict__ zn,
                                              const __bf16* __restrict__ WoT,
                                              const float* __restrict__ bo,
                                              float* __restrict__ pred,
                                              int f)
{
  const int n0 = blockIdx.x << 6;
  f32x4 acc[2][2] = {};
  gemm_core<false>(zn + DIN, KTOT, WoT + (size_t)n0 * DH, DH, DH, acc);
  EPI_SETUP();
  #pragma unroll
  for (int mi = 0; mi < 2; ++mi)
    #pragma unroll
    for (int ni = 0; ni < 2; ++ni)
      #pragma unroll
      for (int r = 0; r < 4; ++r) {
        const int m = wm + mi * 16 + fg * 4 + r;
        const int n = n0 + wn + ni * 16 + fr;
        const float v = acc[mi][ni][r] + bo[n];
        pred[((size_t)m * FUT + f) * DOUT + n] = v;
        zn[(size_t)m * KTOT + n] = (__bf16)v;
      }
}

// ---------------------------------------------------------------------------
extern "C" void kernel_launch(void* const* d_in, const int* in_sizes, int n_in,
                              void* d_out, int out_size, void* d_ws, size_t ws_size,
                              hipStream_t stream)
{
  const float* x  = (const float*)d_in[0];
  const float* Wh = (const float*)d_in[1];
  const float* bh = (const float*)d_in[2];
  const float* Wo = (const float*)d_in[3];
  const float* bo = (const float*)d_in[4];

  char* ws = (char*)d_ws;
  __bf16* WhT  = (__bf16*)ws;                              // [DH][KTOT]   12 MB
  __bf16* WoT  = WhT + (size_t)DH * KTOT;                  // [DOUT][DH]    4 MB
  __bf16* HX   = WoT + (size_t)DOUT * DH;                  // [Sz][Bz][DH] 128 MB
  __bf16* zf   = HX + (size_t)Sz * Bz * DH;                // [2][Bz][KTOT] .8 MB
  __bf16* Hbuf = zf + (size_t)2 * Bz * KTOT;               // [8][Bz][DH]   2 MB

  float* out  = (float*)d_out;
  float* pred = out + (size_t)Bz * Sz * DOUT;

  const dim3 blk(256);

  k_transp<<<dim3(KTOT / 64, DH / 64), blk, 0, stream>>>(Wh, WhT, KTOT, DH);
  k_transp<<<dim3(DH / 64, DOUT / 64), blk, 0, stream>>>(Wo, WoT, DH, DOUT);

  k_sent<<<dim3(256), blk, 0, stream>>>((uint4*)Hbuf,
                                        (int)((size_t)8 * Bz * DH * 2 / 16));

  k_gemm_xw<<<dim3(Sz, DH / 64), blk, 0, stream>>>(x, WhT, bh, HX);

  hipFuncSetAttribute((const void*)k_rnn,
                      hipFuncAttributeMaxDynamicSharedMemorySize, RNN_SMEM);
  {
    const __bf16* a0 = WhT; __bf16* a1 = HX; __bf16* a2 = Hbuf;
    void* args[] = { (void*)&a0, (void*)&a1, (void*)&a2 };
    hipLaunchCooperativeKernel((const void*)k_rnn, dim3(256), blk, args,
                               RNN_SMEM, stream);
  }

  k_out<<<dim3(Sz, DOUT / 64), blk, 0, stream>>>(HX, WoT, bo, out);

  k_finit<<<dim3(Bz), blk, 0, stream>>>(x, HX, zf);
  for (int f = 0; f < FUT; ++f) {
    __bf16* zc = zf + (size_t)(f & 1) * Bz * KTOT;
    __bf16* zn = zf + (size_t)((f & 1) ^ 1) * Bz * KTOT;
    k_fstep<<<dim3(DH / 64), blk, 0, stream>>>(zc, zn, WhT, bh);
    k_fout<<<dim3(DOUT / 64), blk, 0, stream>>>(zn, WoT, bo, pred, f);
  }
}

// Round 7
// 3572.113 us; speedup vs baseline: 1.3254x; 1.3254x over previous
//
#include <hip/hip_runtime.h>
#include <hip/hip_bf16.h>
#include <math.h>

#define Bz   64
#define Sz   512
#define DIN  1024
#define DH   2048
#define DOUT 1024
#define FUT  16
#define KTOT (DIN + DH)   // 3072

typedef __attribute__((ext_vector_type(8))) __bf16 bf16x8;
typedef __attribute__((ext_vector_type(4))) float  f32x4;

union U16x8 { uint4 u; bf16x8 v; };

__device__ __forceinline__ uint4 pack_bf8(float4 a, float4 b) {
  bf16x8 t;
  t[0]=(__bf16)a.x; t[1]=(__bf16)a.y; t[2]=(__bf16)a.z; t[3]=(__bf16)a.w;
  t[4]=(__bf16)b.x; t[5]=(__bf16)b.y; t[6]=(__bf16)b.z; t[7]=(__bf16)b.w;
  U16x8 u; u.v = t; return u.u;
}

// branch-free tanh: 1 - 2/(e^{2x}+1), e^{2x}=2^(2*log2e*x). Saturates to ±1.
__device__ __forceinline__ float fast_tanh(float x) {
  const float e = __builtin_amdgcn_exp2f(2.8853900817779268f * x);
  return 1.0f - 2.0f * __builtin_amdgcn_rcpf(e + 1.0f);
}

// ---------------------------------------------------------------------------
// 64x64-tile GEMM core (unchanged; used by xw/out/future kernels)
// ---------------------------------------------------------------------------
template<bool AF32>
__device__ __forceinline__ void gemm_core(
    const void* __restrict__ Abase, size_t astride,
    const __bf16* __restrict__ Bbase, size_t bstride,
    int K, f32x4 acc[2][2])
{
  __shared__ uint4 Al[2][512];
  __shared__ uint4 Bl[2][512];

  const int tid  = threadIdx.x;
  const int lane = tid & 63;
  const int wave = tid >> 6;
  const int wm = (wave >> 1) << 5;
  const int wn = (wave & 1) << 5;
  const int fr = lane & 15;
  const int fg = lane >> 4;

  const int srow = tid >> 2;
  const int sck  = (tid & 3) << 1;

  const int NK = K >> 6;
  if (NK <= 0) return;

  uint4 ra0, ra1, rb0, rb1;

  auto loadt = [&](int kt) {
    const int kelt = (kt << 6) + (sck << 3);
    if constexpr (AF32) {
      const float* ap = (const float*)Abase + (size_t)srow * astride + kelt;
      float4 a0 = *(const float4*)(ap);
      float4 a1 = *(const float4*)(ap + 4);
      float4 a2 = *(const float4*)(ap + 8);
      float4 a3 = *(const float4*)(ap + 12);
      ra0 = pack_bf8(a0, a1);
      ra1 = pack_bf8(a2, a3);
    } else {
      const __bf16* ap = (const __bf16*)Abase + (size_t)srow * astride + kelt;
      ra0 = *(const uint4*)(ap);
      ra1 = *(const uint4*)(ap + 8);
    }
    const __bf16* bp = Bbase + (size_t)srow * bstride + kelt;
    rb0 = *(const uint4*)(bp);
    rb1 = *(const uint4*)(bp + 8);
  };

  auto storet = [&](int buf) {
    const int x7 = srow & 7;
    Al[buf][srow * 8 + ( sck      ^ x7)] = ra0;
    Al[buf][srow * 8 + ((sck + 1) ^ x7)] = ra1;
    Bl[buf][srow * 8 + ( sck      ^ x7)] = rb0;
    Bl[buf][srow * 8 + ((sck + 1) ^ x7)] = rb1;
  };

  loadt(0);
  storet(0);
  __syncthreads();

  for (int kt = 0; kt < NK; ++kt) {
    const int  cur  = kt & 1;
    const bool more = (kt + 1) < NK;
    if (more) loadt(kt + 1);

    #pragma unroll
    for (int kk = 0; kk < 2; ++kk) {
      bf16x8 af[2], bfrag[2];
      #pragma unroll
      for (int mi = 0; mi < 2; ++mi) {
        const int row = wm + mi * 16 + fr;
        const int ck  = (kk * 4 + fg) ^ (row & 7);
        U16x8 u; u.u = Al[cur][row * 8 + ck]; af[mi] = u.v;
      }
      #pragma unroll
      for (int ni = 0; ni < 2; ++ni) {
        const int row = wn + ni * 16 + fr;
        const int ck  = (kk * 4 + fg) ^ (row & 7);
        U16x8 u; u.u = Bl[cur][row * 8 + ck]; bfrag[ni] = u.v;
      }
      #pragma unroll
      for (int mi = 0; mi < 2; ++mi)
        #pragma unroll
        for (int ni = 0; ni < 2; ++ni)
          acc[mi][ni] = __builtin_amdgcn_mfma_f32_16x16x32_bf16(
              af[mi], bfrag[ni], acc[mi][ni], 0, 0, 0);
    }

    __syncthreads();
    if (more) storet((kt + 1) & 1);
    __syncthreads();
  }
}

#define EPI_SETUP() \
  const int tid = threadIdx.x, lane = tid & 63, wave = tid >> 6; \
  const int wm = (wave >> 1) << 5, wn = (wave & 1) << 5; \
  const int fr = lane & 15, fg = lane >> 4;

// ---------------------------------------------------------------------------
__global__ __launch_bounds__(256) void k_transp(const float* __restrict__ W,
                                                __bf16* __restrict__ WT,
                                                int K, int N)
{
  __shared__ float T[64][65];
  const int k0 = blockIdx.x << 6, n0 = blockIdx.y << 6;
  const int c = threadIdx.x & 63, r4 = threadIdx.x >> 6;
  #pragma unroll
  for (int rr = 0; rr < 16; ++rr) {
    const int r = rr * 4 + r4;
    T[r][c] = W[(size_t)(k0 + r) * N + n0 + c];
  }
  __syncthreads();
  #pragma unroll
  for (int rr = 0; rr < 16; ++rr) {
    const int r = rr * 4 + r4;
    WT[(size_t)(n0 + r) * K + k0 + c] = (__bf16)T[c][r];
  }
}

// ---------------------------------------------------------------------------
// Phase A: HX[s][b][n] = bf16( x[b][s][:] . Wx[:,n] + bh[n] )   (pre-tanh)
// ---------------------------------------------------------------------------
__global__ __launch_bounds__(256) void k_gemm_xw(const float* __restrict__ x,
                                                 const __bf16* __restrict__ WhT,
                                                 const float* __restrict__ bh,
                                                 __bf16* __restrict__ HX)
{
  const int s = blockIdx.x;
  const int n0 = blockIdx.y << 6;
  f32x4 acc[2][2] = {};
  gemm_core<true>(x + (size_t)s * DIN, (size_t)Sz * DIN,
                  WhT + (size_t)n0 * KTOT, KTOT, DIN, acc);
  EPI_SETUP();
  __bf16* out = HX + (size_t)s * Bz * DH;
  #pragma unroll
  for (int mi = 0; mi < 2; ++mi)
    #pragma unroll
    for (int ni = 0; ni < 2; ++ni)
      #pragma unroll
      for (int r = 0; r < 4; ++r) {
        const int m = wm + mi * 16 + fg * 4 + r;
        const int n = n0 + wn + ni * 16 + fr;
        out[(size_t)m * DH + n] = (__bf16)(acc[mi][ni][r] + bh[n]);
      }
}

// ---------------------------------------------------------------------------
// Persistent RNN recurrence. r6 -> r7: REVERT to r5's proven flag protocol,
// REDESIGN compute for lower contention:
//   * 128 blocks x 512 threads (8 waves). Block (mb, nb): rows 16mb..+16,
//     cols 64nb..+64. Whh slice lives in VGPRs as MFMA B-fragments
//     (8 waves x K-256 x 64 cols = 128 VGPR/thread) — no LDS weight reads.
//   * Wave w owns K-eighth [256w..256w+256): polls only its 4 producers'
//     flags, then 8 cached dwordx4 A-loads, 32 MFMA.
//   * 8-wave K-reduce via padded LDS (stride 66 -> <=2-way conflicts).
//   * Protocol identical to r5: sc0sc1 XW prefetch (no stale L2 fill),
//     sc0sc1 h store -> vmcnt(0) -> barrier -> tid0 flag store; consumers
//     poll flags sc0sc1 then read A cached (L2-dedup within XCD).
// ---------------------------------------------------------------------------
__global__ __launch_bounds__(512, 2) void k_rnn(const __bf16* __restrict__ WhT,
                                                __bf16* __restrict__ HX,
                                                unsigned int* __restrict__ flags)
{
  __shared__ __align__(16) float RED[8 * 1056];   // 8 planes x [16][66]

  const int mb    = blockIdx.x & 3;
  const int nb    = blockIdx.x >> 2;      // 0..31
  const int nbase = nb << 6;              // 64-col slice
  const int tid   = threadIdx.x;
  const int lane  = tid & 63;
  const int w     = tid >> 6;             // 0..7 (K-eighth owner)
  const int l15   = lane & 15;
  const int l4    = lane >> 4;
  const int wavek = w << 8;               // K range [wavek, wavek+256)

  // ---- Whh slice resident in VGPRs as B-fragments ----
  bf16x8 wf[8][4];
  {
    const __bf16* wb = WhT + (size_t)(nbase + l15) * KTOT + DIN + wavek + (l4 << 3);
    #pragma unroll
    for (int kk = 0; kk < 8; ++kk)
      #pragma unroll
      for (int nt = 0; nt < 4; ++nt)
        wf[kk][nt] = *(const bf16x8*)(wb + (size_t)nt * 16 * KTOT + kk * 32);
  }

  // output mapping (reduce phase): 512 threads = 16 rows x 32 col-pairs
  const int orow = tid >> 5;
  const int cp   = tid & 31;
  const int grow = (mb << 4) + orow;
  const int gcol = nbase + (cp << 1);

  for (int t = 0; t < Sz; ++t) {
    __bf16* Hc = HX + (size_t)t * Bz * DH;

    // XW prefetch via sc0sc1 (no L2 fill of soon-to-be-overwritten lines)
    unsigned int xwp;
    asm volatile("global_load_dword %0, %1, off sc0 sc1"
                 : "=v"(xwp)
                 : "v"((const void*)(Hc + (size_t)grow * DH + gcol))
                 : "memory");

    f32x4 acc[4] = {};

    if (t > 0) {
      // poll this wave's 4 producers (cols [256w..256w+256) = nb' in [4w..4w+4))
      const unsigned int* fl = flags
          + (((size_t)(t - 1) * 4 + mb) << 7) + (((w << 2) + (lane & 3)) << 2);
      for (;;) {
        unsigned int f;
        asm volatile("global_load_dword %0, %1, off sc0 sc1\n\t"
                     "s_waitcnt vmcnt(0)"
                     : "=v"(f) : "v"((const void*)fl) : "memory");
        if (__all((int)(f == 1u))) break;
        __builtin_amdgcn_s_sleep(1);
      }

      // cached A-loads (L2-dedup within XCD; no stale copies per r5 argument)
      const __bf16* Hp = HX + (size_t)(t - 1) * Bz * DH
                       + (size_t)((mb << 4) + l15) * DH + wavek + (l4 << 3);
      bf16x8 a[8];
      #pragma unroll
      for (int kk = 0; kk < 8; ++kk)
        a[kk] = *(const bf16x8*)(Hp + kk * 32);

      #pragma unroll
      for (int kk = 0; kk < 8; ++kk)
        #pragma unroll
        for (int nt = 0; nt < 4; ++nt)
          acc[nt] = __builtin_amdgcn_mfma_f32_16x16x32_bf16(
              a[kk], wf[kk][nt], acc[nt], 0, 0, 0);
    }

    // ---- 8-wave K reduction through padded LDS ----
    #pragma unroll
    for (int nt = 0; nt < 4; ++nt)
      #pragma unroll
      for (int r = 0; r < 4; ++r)
        RED[w * 1056 + ((l4 << 2) + r) * 66 + (nt << 4) + l15] = acc[nt][r];
    __syncthreads();

    float sx = 0.f, sy = 0.f;
    #pragma unroll
    for (int p = 0; p < 8; ++p) {
      const float2 v = *(const float2*)&RED[p * 1056 + orow * 66 + (cp << 1)];
      sx += v.x; sy += v.y;
    }

    // wait the XW prefetch (tied operand orders the wait before use)
    asm volatile("s_waitcnt vmcnt(0)" : "+v"(xwp) :: "memory");
    union { unsigned int u; __bf16 h[2]; } ux; ux.u = xwp;
    union { unsigned int u; __bf16 h[2]; } po;
    po.h[0] = (__bf16)fast_tanh(sx + (float)ux.h[0]);
    po.h[1] = (__bf16)fast_tanh(sy + (float)ux.h[1]);

    // h store at the coherence point, then publish
    asm volatile("global_store_dword %0, %1, off sc0 sc1"
                 :: "v"((void*)(Hc + (size_t)grow * DH + gcol)), "v"(po.u)
                 : "memory");
    asm volatile("s_waitcnt vmcnt(0)" ::: "memory");   // acked at LLC
    __syncthreads();   // whole block done (also RED WAR for next iter)
    if (tid == 0) {
      unsigned int* fp = flags + (((size_t)t * 4 + mb) << 7) + (nb << 2);
      asm volatile("global_store_dword %0, %1, off sc0 sc1"
                   :: "v"((void*)fp), "v"(1u) : "memory");
    }
  }
}

// ---------------------------------------------------------------------------
// Phase C: out[b][s][n] = HX[s][b][:] . Wo[:,n] + bo[n]
// ---------------------------------------------------------------------------
__global__ __launch_bounds__(256) void k_out(const __bf16* __restrict__ HX,
                                             const __bf16* __restrict__ WoT,
                                             const float* __restrict__ bo,
                                             float* __restrict__ out)
{
  const int s = blockIdx.x;
  const int n0 = blockIdx.y << 6;
  f32x4 acc[2][2] = {};
  gemm_core<false>(HX + (size_t)s * Bz * DH, DH,
                   WoT + (size_t)n0 * DH, DH, DH, acc);
  EPI_SETUP();
  #pragma unroll
  for (int mi = 0; mi < 2; ++mi)
    #pragma unroll
    for (int ni = 0; ni < 2; ++ni)
      #pragma unroll
      for (int r = 0; r < 4; ++r) {
        const int m = wm + mi * 16 + fg * 4 + r;
        const int n = n0 + wn + ni * 16 + fr;
        out[((size_t)m * Sz + s) * DOUT + n] = acc[mi][ni][r] + bo[n];
      }
}

// ---------------------------------------------------------------------------
__global__ __launch_bounds__(256) void k_finit(const float* __restrict__ x,
                                               const __bf16* __restrict__ HX,
                                               __bf16* __restrict__ zf0)
{
  const int b = blockIdx.x;
  for (int k = threadIdx.x; k < DIN; k += 256)
    zf0[(size_t)b * KTOT + k] =
        (__bf16)x[((size_t)b * Sz + (Sz - 1)) * DIN + k];
  for (int k = threadIdx.x; k < DH; k += 256)
    zf0[(size_t)b * KTOT + DIN + k] =
        HX[(size_t)(Sz - 1) * Bz * DH + (size_t)b * DH + k];
}

__global__ __launch_bounds__(256) void k_fstep(const __bf16* __restrict__ zc,
                                               __bf16* __restrict__ zn,
                                               const __bf16* __restrict__ WhT,
                                               const float* __restrict__ bh)
{
  const int n0 = blockIdx.x << 6;
  f32x4 acc[2][2] = {};
  gemm_core<false>(zc, KTOT, WhT + (size_t)n0 * KTOT, KTOT, KTOT, acc);
  EPI_SETUP();
  #pragma unroll
  for (int mi = 0; mi < 2; ++mi)
    #pragma unroll
    for (int ni = 0; ni < 2; ++ni)
      #pragma unroll
      for (int r = 0; r < 4; ++r) {
        const int m = wm + mi * 16 + fg * 4 + r;
        const int n = n0 + wn + ni * 16 + fr;
        zn[(size_t)m * KTOT + DIN + n] = (__bf16)fast_tanh(acc[mi][ni][r] + bh[n]);
      }
}

__global__ __launch_bounds__(256) void k_fout(__bf16* __restrict__ zn,
                                              const __bf16* __restrict__ WoT,
                                              const float* __restrict__ bo,
                                              float* __restrict__ pred,
                                              int f)
{
  const int n0 = blockIdx.x << 6;
  f32x4 acc[2][2] = {};
  gemm_core<false>(zn + DIN, KTOT, WoT + (size_t)n0 * DH, DH, DH, acc);
  EPI_SETUP();
  #pragma unroll
  for (int mi = 0; mi < 2; ++mi)
    #pragma unroll
    for (int ni = 0; ni < 2; ++ni)
      #pragma unroll
      for (int r = 0; r < 4; ++r) {
        const int m = wm + mi * 16 + fg * 4 + r;
        const int n = n0 + wn + ni * 16 + fr;
        const float v = acc[mi][ni][r] + bo[n];
        pred[((size_t)m * FUT + f) * DOUT + n] = v;
        zn[(size_t)m * KTOT + n] = (__bf16)v;
      }
}

// ---------------------------------------------------------------------------
extern "C" void kernel_launch(void* const* d_in, const int* in_sizes, int n_in,
                              void* d_out, int out_size, void* d_ws, size_t ws_size,
                              hipStream_t stream)
{
  const float* x  = (const float*)d_in[0];
  const float* Wh = (const float*)d_in[1];
  const float* bh = (const float*)d_in[2];
  const float* Wo = (const float*)d_in[3];
  const float* bo = (const float*)d_in[4];

  char* ws = (char*)d_ws;
  __bf16* WhT = (__bf16*)ws;                               // [DH][KTOT]   12 MB
  __bf16* WoT = WhT + (size_t)DH * KTOT;                   // [DOUT][DH]    4 MB
  __bf16* HX  = WoT + (size_t)DOUT * DH;                   // [Sz][Bz][DH] 128 MB
  __bf16* zf  = HX + (size_t)Sz * Bz * DH;                 // [2][Bz][KTOT] .8 MB
  unsigned int* flags = (unsigned int*)(zf + (size_t)2 * Bz * KTOT); // 1 MB

  float* out  = (float*)d_out;
  float* pred = out + (size_t)Bz * Sz * DOUT;

  const dim3 blk(256);

  k_transp<<<dim3(KTOT / 64, DH / 64), blk, 0, stream>>>(Wh, WhT, KTOT, DH);
  k_transp<<<dim3(DH / 64, DOUT / 64), blk, 0, stream>>>(Wo, WoT, DH, DOUT);

  hipMemsetAsync(flags, 0, (size_t)Sz * 4 * 128 * sizeof(unsigned int), stream);

  k_gemm_xw<<<dim3(Sz, DH / 64), blk, 0, stream>>>(x, WhT, bh, HX);

  {
    const __bf16* a0 = WhT; __bf16* a1 = HX; unsigned int* a2 = flags;
    void* args[] = { (void*)&a0, (void*)&a1, (void*)&a2 };
    hipLaunchCooperativeKernel((const void*)k_rnn, dim3(128), dim3(512), args,
                               0, stream);
  }

  k_out<<<dim3(Sz, DOUT / 64), blk, 0, stream>>>(HX, WoT, bo, out);

  k_finit<<<dim3(Bz), blk, 0, stream>>>(x, HX, zf);
  for (int f = 0; f < FUT; ++f) {
    __bf16* zc = zf + (size_t)(f & 1) * Bz * KTOT;
    __bf16* zn = zf + (size_t)((f & 1) ^ 1) * Bz * KTOT;
    k_fstep<<<dim3(DH / 64), blk, 0, stream>>>(zc, zn, WhT, bh);
    k_fout<<<dim3(DOUT / 64), blk, 0, stream>>>(zn, WoT, bo, pred, f);
  }
}

// Round 8
// 3211.877 us; speedup vs baseline: 1.4740x; 1.1122x over previous
//
#include <hip/hip_runtime.h>
#include <hip/hip_bf16.h>
#include <math.h>

#define Bz   64
#define Sz   512
#define DIN  1024
#define DH   2048
#define DOUT 1024
#define FUT  16
#define KTOT (DIN + DH)   // 3072

typedef __attribute__((ext_vector_type(8))) __bf16 bf16x8;
typedef __attribute__((ext_vector_type(4))) float  f32x4;

union U16x8 { uint4 u; bf16x8 v; };

__device__ __forceinline__ uint4 pack_bf8(float4 a, float4 b) {
  bf16x8 t;
  t[0]=(__bf16)a.x; t[1]=(__bf16)a.y; t[2]=(__bf16)a.z; t[3]=(__bf16)a.w;
  t[4]=(__bf16)b.x; t[5]=(__bf16)b.y; t[6]=(__bf16)b.z; t[7]=(__bf16)b.w;
  U16x8 u; u.v = t; return u.u;
}

// branch-free tanh: 1 - 2/(e^{2x}+1). Saturates to ±1.
__device__ __forceinline__ float fast_tanh(float x) {
  const float e = __builtin_amdgcn_exp2f(2.8853900817779268f * x);
  return 1.0f - 2.0f * __builtin_amdgcn_rcpf(e + 1.0f);
}

// async global->LDS, 16B per lane (dest = wave-uniform base + lane*16)
__device__ __forceinline__ void gload16(const void* g, void* l) {
  __builtin_amdgcn_global_load_lds(
      (const __attribute__((address_space(1))) unsigned int*)g,
      (__attribute__((address_space(3))) unsigned int*)l, 16, 0, 0);
}

// ---------------------------------------------------------------------------
// 64x64-tile GEMM core (used by future-phase kernels only now)
// ---------------------------------------------------------------------------
template<bool AF32>
__device__ __forceinline__ void gemm_core(
    const void* __restrict__ Abase, size_t astride,
    const __bf16* __restrict__ Bbase, size_t bstride,
    int K, f32x4 acc[2][2])
{
  __shared__ uint4 Al[2][512];
  __shared__ uint4 Bl[2][512];

  const int tid  = threadIdx.x;
  const int lane = tid & 63;
  const int wave = tid >> 6;
  const int wm = (wave >> 1) << 5;
  const int wn = (wave & 1) << 5;
  const int fr = lane & 15;
  const int fg = lane >> 4;

  const int srow = tid >> 2;
  const int sck  = (tid & 3) << 1;

  const int NK = K >> 6;
  if (NK <= 0) return;

  uint4 ra0, ra1, rb0, rb1;

  auto loadt = [&](int kt) {
    const int kelt = (kt << 6) + (sck << 3);
    if constexpr (AF32) {
      const float* ap = (const float*)Abase + (size_t)srow * astride + kelt;
      float4 a0 = *(const float4*)(ap);
      float4 a1 = *(const float4*)(ap + 4);
      float4 a2 = *(const float4*)(ap + 8);
      float4 a3 = *(const float4*)(ap + 12);
      ra0 = pack_bf8(a0, a1);
      ra1 = pack_bf8(a2, a3);
    } else {
      const __bf16* ap = (const __bf16*)Abase + (size_t)srow * astride + kelt;
      ra0 = *(const uint4*)(ap);
      ra1 = *(const uint4*)(ap + 8);
    }
    const __bf16* bp = Bbase + (size_t)srow * bstride + kelt;
    rb0 = *(const uint4*)(bp);
    rb1 = *(const uint4*)(bp + 8);
  };

  auto storet = [&](int buf) {
    const int x7 = srow & 7;
    Al[buf][srow * 8 + ( sck      ^ x7)] = ra0;
    Al[buf][srow * 8 + ((sck + 1) ^ x7)] = ra1;
    Bl[buf][srow * 8 + ( sck      ^ x7)] = rb0;
    Bl[buf][srow * 8 + ((sck + 1) ^ x7)] = rb1;
  };

  loadt(0);
  storet(0);
  __syncthreads();

  for (int kt = 0; kt < NK; ++kt) {
    const int  cur  = kt & 1;
    const bool more = (kt + 1) < NK;
    if (more) loadt(kt + 1);

    #pragma unroll
    for (int kk = 0; kk < 2; ++kk) {
      bf16x8 af[2], bfrag[2];
      #pragma unroll
      for (int mi = 0; mi < 2; ++mi) {
        const int row = wm + mi * 16 + fr;
        const int ck  = (kk * 4 + fg) ^ (row & 7);
        U16x8 u; u.u = Al[cur][row * 8 + ck]; af[mi] = u.v;
      }
      #pragma unroll
      for (int ni = 0; ni < 2; ++ni) {
        const int row = wn + ni * 16 + fr;
        const int ck  = (kk * 4 + fg) ^ (row & 7);
        U16x8 u; u.u = Bl[cur][row * 8 + ck]; bfrag[ni] = u.v;
      }
      #pragma unroll
      for (int mi = 0; mi < 2; ++mi)
        #pragma unroll
        for (int ni = 0; ni < 2; ++ni)
          acc[mi][ni] = __builtin_amdgcn_mfma_f32_16x16x32_bf16(
              af[mi], bfrag[ni], acc[mi][ni], 0, 0, 0);
    }

    __syncthreads();
    if (more) storet((kt + 1) & 1);
    __syncthreads();
  }
}

#define EPI_SETUP() \
  const int tid = threadIdx.x, lane = tid & 63, wave = tid >> 6; \
  const int wm = (wave >> 1) << 5, wn = (wave & 1) << 5; \
  const int fr = lane & 15, fg = lane >> 4;

// ---------------------------------------------------------------------------
__global__ __launch_bounds__(256) void k_transp(const float* __restrict__ W,
                                                __bf16* __restrict__ WT,
                                                int K, int N)
{
  __shared__ float T[64][65];
  const int k0 = blockIdx.x << 6, n0 = blockIdx.y << 6;
  const int c = threadIdx.x & 63, r4 = threadIdx.x >> 6;
  #pragma unroll
  for (int rr = 0; rr < 16; ++rr) {
    const int r = rr * 4 + r4;
    T[r][c] = W[(size_t)(k0 + r) * N + n0 + c];
  }
  __syncthreads();
  #pragma unroll
  for (int rr = 0; rr < 16; ++rr) {
    const int r = rr * 4 + r4;
    WT[(size_t)(n0 + r) * K + k0 + c] = (__bf16)T[c][r];
  }
}

// ---------------------------------------------------------------------------
// Phase A (m97-style 128x128): HX[s][b][n] = bf16(x_row . Wx[:,n] + bh[n])
//   A = x viewed as [M=32768][K=1024] (row = b*512+s), fp32, reg-staged+packed
//   B = WhT rows (stride KTOT, k in [0,DIN)), staged via global_load_lds
//   grid (16 n-tiles, 256 m-tiles): XCD = nt%8 -> B panel pinned per XCD L2
// ---------------------------------------------------------------------------
__global__ __launch_bounds__(256) void k_xw128(const float* __restrict__ x,
                                               const __bf16* __restrict__ WhT,
                                               const float* __restrict__ bh,
                                               __bf16* __restrict__ HX)
{
  __shared__ __align__(16) uint4 As[1024];   // [128 rows][8 chunks] bf16
  __shared__ __align__(16) uint4 Bs[1024];

  const int n0 = blockIdx.x << 7;
  const int m0 = blockIdx.y << 7;
  const int tid = threadIdx.x, lane = tid & 63, w = tid >> 6;
  const int wr = w >> 1, wc = w & 1;
  const int fr = lane & 15, fg = lane >> 4;

  const int sr  = tid >> 3;            // staging row (of 128, +32j)
  const int sq  = tid & 7;             // LDS chunk col
  const int sq2 = sq ^ (sr & 7);       // swizzled source chunk col

  f32x4 acc[4][4] = {};

  for (int kt = 0; kt < DIN / 64; ++kt) {
    const int ko = kt << 6;
    #pragma unroll
    for (int j = 0; j < 4; ++j) {
      // A: fp32 -> bf16 pack, reg-staged, swizzle applied at write
      const float* ap = x + (size_t)(m0 + sr + 32 * j) * DIN + ko + (sq2 << 3);
      float4 a0 = *(const float4*)ap;
      float4 a1 = *(const float4*)(ap + 4);
      As[((sr + 32 * j) << 3) + sq] = pack_bf8(a0, a1);
      // B: async gload, swizzle applied at source address
      gload16(WhT + (size_t)(n0 + sr + 32 * j) * KTOT + ko + (sq2 << 3),
              (char*)Bs + (tid << 4) + (j << 12));
    }
    __syncthreads();
    #pragma unroll
    for (int kk = 0; kk < 2; ++kk) {
      bf16x8 af[4], bf_[4];
      const int kq = (kk << 2) + fg;
      #pragma unroll
      for (int mi = 0; mi < 4; ++mi) {
        const int row = (wr << 6) + (mi << 4) + fr;
        U16x8 u; u.u = As[(row << 3) + (kq ^ (row & 7))]; af[mi] = u.v;
      }
      #pragma unroll
      for (int ni = 0; ni < 4; ++ni) {
        const int row = (wc << 6) + (ni << 4) + fr;
        U16x8 u; u.u = Bs[(row << 3) + (kq ^ (row & 7))]; bf_[ni] = u.v;
      }
      #pragma unroll
      for (int mi = 0; mi < 4; ++mi)
        #pragma unroll
        for (int ni = 0; ni < 4; ++ni)
          acc[mi][ni] = __builtin_amdgcn_mfma_f32_16x16x32_bf16(
              af[mi], bf_[ni], acc[mi][ni], 0, 0, 0);
    }
    __syncthreads();
  }

  #pragma unroll
  for (int ni = 0; ni < 4; ++ni) {
    const int n = n0 + (wc << 6) + (ni << 4) + fr;
    const float bn = bh[n];
    #pragma unroll
    for (int mi = 0; mi < 4; ++mi)
      #pragma unroll
      for (int rr = 0; rr < 4; ++rr) {
        const int gf = m0 + (wr << 6) + (mi << 4) + (fg << 2) + rr;
        const int b = gf >> 9, s = gf & 511;     // row = b*512+s
        HX[((size_t)s * Bz + b) * DH + n] = (__bf16)(acc[mi][ni][rr] + bn);
      }
  }
}

// ---------------------------------------------------------------------------
// Phase C (m97-style 128x128): out[b][s][n] = HX_row . Wo[:,n] + bo[n]
//   A = HX viewed as [M=32768][K=2048] (row = s*64+b), bf16, gload_lds
//   B = WoT rows (stride DH), gload_lds. grid (8 n-tiles, 256 m-tiles)
// ---------------------------------------------------------------------------
__global__ __launch_bounds__(256) void k_out128(const __bf16* __restrict__ HX,
                                                const __bf16* __restrict__ WoT,
                                                const float* __restrict__ bo,
                                                float* __restrict__ out)
{
  __shared__ __align__(16) uint4 As[1024];
  __shared__ __align__(16) uint4 Bs[1024];

  const int n0 = blockIdx.x << 7;
  const int m0 = blockIdx.y << 7;
  const int tid = threadIdx.x, lane = tid & 63, w = tid >> 6;
  const int wr = w >> 1, wc = w & 1;
  const int fr = lane & 15, fg = lane >> 4;

  const int sr  = tid >> 3;
  const int sq  = tid & 7;
  const int sq2 = sq ^ (sr & 7);

  f32x4 acc[4][4] = {};

  for (int kt = 0; kt < DH / 64; ++kt) {
    const int ko = kt << 6;
    #pragma unroll
    for (int j = 0; j < 4; ++j) {
      gload16(HX + (size_t)(m0 + sr + 32 * j) * DH + ko + (sq2 << 3),
              (char*)As + (tid << 4) + (j << 12));
      gload16(WoT + (size_t)(n0 + sr + 32 * j) * DH + ko + (sq2 << 3),
              (char*)Bs + (tid << 4) + (j << 12));
    }
    __syncthreads();
    #pragma unroll
    for (int kk = 0; kk < 2; ++kk) {
      bf16x8 af[4], bf_[4];
      const int kq = (kk << 2) + fg;
      #pragma unroll
      for (int mi = 0; mi < 4; ++mi) {
        const int row = (wr << 6) + (mi << 4) + fr;
        U16x8 u; u.u = As[(row << 3) + (kq ^ (row & 7))]; af[mi] = u.v;
      }
      #pragma unroll
      for (int ni = 0; ni < 4; ++ni) {
        const int row = (wc << 6) + (ni << 4) + fr;
        U16x8 u; u.u = Bs[(row << 3) + (kq ^ (row & 7))]; bf_[ni] = u.v;
      }
      #pragma unroll
      for (int mi = 0; mi < 4; ++mi)
        #pragma unroll
        for (int ni = 0; ni < 4; ++ni)
          acc[mi][ni] = __builtin_amdgcn_mfma_f32_16x16x32_bf16(
              af[mi], bf_[ni], acc[mi][ni], 0, 0, 0);
    }
    __syncthreads();
  }

  #pragma unroll
  for (int ni = 0; ni < 4; ++ni) {
    const int n = n0 + (wc << 6) + (ni << 4) + fr;
    const float bn = bo[n];
    #pragma unroll
    for (int mi = 0; mi < 4; ++mi)
      #pragma unroll
      for (int rr = 0; rr < 4; ++rr) {
        const int gf = m0 + (wr << 6) + (mi << 4) + (fg << 2) + rr;
        const int s = gf >> 6, b = gf & 63;      // row = s*64+b
        out[((size_t)b * Sz + s) * DOUT + n] = acc[mi][ni][rr] + bn;
      }
  }
}

// ---------------------------------------------------------------------------
// Persistent RNN recurrence. r7 -> r8: Whh PINNED IN AGPRs via inline-asm
// MFMA with "a"-constrained B operand (defeats the remat that left
// VGPR_Count=84 and re-streamed 256KB/block/step of weights from L2).
// Protocol unchanged from r7 (proven): sc0sc1 XW prefetch, flag poll,
// cached A-loads, sc0sc1 h store + ack + flag publish.
// ---------------------------------------------------------------------------
__global__ __launch_bounds__(512, 2) void k_rnn(const __bf16* __restrict__ WhT,
                                                __bf16* __restrict__ HX,
                                                unsigned int* __restrict__ flags)
{
  __shared__ __align__(16) float RED[8 * 1056];   // 8 planes x [16][66]

  const int mb    = blockIdx.x & 3;
  const int nb    = blockIdx.x >> 2;      // 0..31
  const int nbase = nb << 6;              // 64-col slice
  const int tid   = threadIdx.x;
  const int lane  = tid & 63;
  const int w     = tid >> 6;             // 0..7 (K-eighth owner)
  const int l15   = lane & 15;
  const int l4    = lane >> 4;
  const int wavek = w << 8;               // K range [wavek, wavek+256)

  // ---- Whh slice resident in AGPRs as B-fragments (128 AGPR/thread) ----
  bf16x8 wf[8][4];
  {
    const __bf16* wb = WhT + (size_t)(nbase + l15) * KTOT + DIN + wavek + (l4 << 3);
    #pragma unroll
    for (int kk = 0; kk < 8; ++kk)
      #pragma unroll
      for (int nt = 0; nt < 4; ++nt)
        wf[kk][nt] = *(const bf16x8*)(wb + (size_t)nt * 16 * KTOT + kk * 32);
  }

  // output mapping (reduce phase): 512 threads = 16 rows x 32 col-pairs
  const int orow = tid >> 5;
  const int cp   = tid & 31;
  const int grow = (mb << 4) + orow;
  const int gcol = nbase + (cp << 1);

  for (int t = 0; t < Sz; ++t) {
    __bf16* Hc = HX + (size_t)t * Bz * DH;

    // XW prefetch via sc0sc1 (no L2 fill of soon-to-be-overwritten lines)
    unsigned int xwp;
    asm volatile("global_load_dword %0, %1, off sc0 sc1"
                 : "=v"(xwp)
                 : "v"((const void*)(Hc + (size_t)grow * DH + gcol))
                 : "memory");

    f32x4 acc[4] = {};

    if (t > 0) {
      // poll this wave's 4 producers
      const unsigned int* fl = flags
          + (((size_t)(t - 1) * 4 + mb) << 7) + (((w << 2) + (lane & 3)) << 2);
      for (;;) {
        unsigned int f;
        asm volatile("global_load_dword %0, %1, off sc0 sc1\n\t"
                     "s_waitcnt vmcnt(0)"
                     : "=v"(f) : "v"((const void*)fl) : "memory");
        if (__all((int)(f == 1u))) break;
        __builtin_amdgcn_s_sleep(1);
      }

      // cached A-loads (L2-dedup within XCD)
      const __bf16* Hp = HX + (size_t)(t - 1) * Bz * DH
                       + (size_t)((mb << 4) + l15) * DH + wavek + (l4 << 3);
      bf16x8 a[8];
      #pragma unroll
      for (int kk = 0; kk < 8; ++kk)
        a[kk] = *(const bf16x8*)(Hp + kk * 32);

      #pragma unroll
      for (int kk = 0; kk < 8; ++kk)
        #pragma unroll
        for (int nt = 0; nt < 4; ++nt)
          asm("v_mfma_f32_16x16x32_bf16 %0, %1, %2, %0"
              : "+v"(acc[nt]) : "v"(a[kk]), "a"(wf[kk][nt]));
    }

    // ---- 8-wave K reduction through padded LDS ----
    #pragma unroll
    for (int nt = 0; nt < 4; ++nt)
      #pragma unroll
      for (int r = 0; r < 4; ++r)
        RED[w * 1056 + ((l4 << 2) + r) * 66 + (nt << 4) + l15] = acc[nt][r];
    __syncthreads();

    float sx = 0.f, sy = 0.f;
    #pragma unroll
    for (int p = 0; p < 8; ++p) {
      const float2 v = *(const float2*)&RED[p * 1056 + orow * 66 + (cp << 1)];
      sx += v.x; sy += v.y;
    }

    asm volatile("s_waitcnt vmcnt(0)" : "+v"(xwp) :: "memory");
    union { unsigned int u; __bf16 h[2]; } ux; ux.u = xwp;
    union { unsigned int u; __bf16 h[2]; } po;
    po.h[0] = (__bf16)fast_tanh(sx + (float)ux.h[0]);
    po.h[1] = (__bf16)fast_tanh(sy + (float)ux.h[1]);

    asm volatile("global_store_dword %0, %1, off sc0 sc1"
                 :: "v"((void*)(Hc + (size_t)grow * DH + gcol)), "v"(po.u)
                 : "memory");
    asm volatile("s_waitcnt vmcnt(0)" ::: "memory");   // acked at LLC
    __syncthreads();
    if (tid == 0) {
      unsigned int* fp = flags + (((size_t)t * 4 + mb) << 7) + (nb << 2);
      asm volatile("global_store_dword %0, %1, off sc0 sc1"
                   :: "v"((void*)fp), "v"(1u) : "memory");
    }
  }
}

// ---------------------------------------------------------------------------
__global__ __launch_bounds__(256) void k_finit(const float* __restrict__ x,
                                               const __bf16* __restrict__ HX,
                                               __bf16* __restrict__ zf0)
{
  const int b = blockIdx.x;
  for (int k = threadIdx.x; k < DIN; k += 256)
    zf0[(size_t)b * KTOT + k] =
        (__bf16)x[((size_t)b * Sz + (Sz - 1)) * DIN + k];
  for (int k = threadIdx.x; k < DH; k += 256)
    zf0[(size_t)b * KTOT + DIN + k] =
        HX[(size_t)(Sz - 1) * Bz * DH + (size_t)b * DH + k];
}

__global__ __launch_bounds__(256) void k_fstep(const __bf16* __restrict__ zc,
                                               __bf16* __restrict__ zn,
                                               const __bf16* __restrict__ WhT,
                                               const float* __restrict__ bh)
{
  const int n0 = blockIdx.x << 6;
  f32x4 acc[2][2] = {};
  gemm_core<false>(zc, KTOT, WhT + (size_t)n0 * KTOT, KTOT, KTOT, acc);
  EPI_SETUP();
  #pragma unroll
  for (int mi = 0; mi < 2; ++mi)
    #pragma unroll
    for (int ni = 0; ni < 2; ++ni)
      #pragma unroll
      for (int r = 0; r < 4; ++r) {
        const int m = wm + mi * 16 + fg * 4 + r;
        const int n = n0 + wn + ni * 16 + fr;
        zn[(size_t)m * KTOT + DIN + n] = (__bf16)fast_tanh(acc[mi][ni][r] + bh[n]);
      }
}

__global__ __launch_bounds__(256) void k_fout(__bf16* __restrict__ zn,
                                              const __bf16* __restrict__ WoT,
                                              const float* __restrict__ bo,
                                              float* __restrict__ pred,
                                              int f)
{
  const int n0 = blockIdx.x << 6;
  f32x4 acc[2][2] = {};
  gemm_core<false>(zn + DIN, KTOT, WoT + (size_t)n0 * DH, DH, DH, acc);
  EPI_SETUP();
  #pragma unroll
  for (int mi = 0; mi < 2; ++mi)
    #pragma unroll
    for (int ni = 0; ni < 2; ++ni)
      #pragma unroll
      for (int r = 0; r < 4; ++r) {
        const int m = wm + mi * 16 + fg * 4 + r;
        const int n = n0 + wn + ni * 16 + fr;
        const float v = acc[mi][ni][r] + bo[n];
        pred[((size_t)m * FUT + f) * DOUT + n] = v;
        zn[(size_t)m * KTOT + n] = (__bf16)v;
      }
}

// ---------------------------------------------------------------------------
extern "C" void kernel_launch(void* const* d_in, const int* in_sizes, int n_in,
                              void* d_out, int out_size, void* d_ws, size_t ws_size,
                              hipStream_t stream)
{
  const float* x  = (const float*)d_in[0];
  const float* Wh = (const float*)d_in[1];
  const float* bh = (const float*)d_in[2];
  const float* Wo = (const float*)d_in[3];
  const float* bo = (const float*)d_in[4];

  char* ws = (char*)d_ws;
  __bf16* WhT = (__bf16*)ws;                               // [DH][KTOT]   12 MB
  __bf16* WoT = WhT + (size_t)DH * KTOT;                   // [DOUT][DH]    4 MB
  __bf16* HX  = WoT + (size_t)DOUT * DH;                   // [Sz][Bz][DH] 128 MB
  __bf16* zf  = HX + (size_t)Sz * Bz * DH;                 // [2][Bz][KTOT] .8 MB
  unsigned int* flags = (unsigned int*)(zf + (size_t)2 * Bz * KTOT); // 1 MB

  float* out  = (float*)d_out;
  float* pred = out + (size_t)Bz * Sz * DOUT;

  const dim3 blk(256);

  k_transp<<<dim3(KTOT / 64, DH / 64), blk, 0, stream>>>(Wh, WhT, KTOT, DH);
  k_transp<<<dim3(DH / 64, DOUT / 64), blk, 0, stream>>>(Wo, WoT, DH, DOUT);

  hipMemsetAsync(flags, 0, (size_t)Sz * 4 * 128 * sizeof(unsigned int), stream);

  k_xw128<<<dim3(DH / 128, (Bz * Sz) / 128), blk, 0, stream>>>(x, WhT, bh, HX);

  {
    const __bf16* a0 = WhT; __bf16* a1 = HX; unsigned int* a2 = flags;
    void* args[] = { (void*)&a0, (void*)&a1, (void*)&a2 };
    hipLaunchCooperativeKernel((const void*)k_rnn, dim3(128), dim3(512), args,
                               0, stream);
  }

  k_out128<<<dim3(DOUT / 128, (Bz * Sz) / 128), blk, 0, stream>>>(HX, WoT, bo, out);

  k_finit<<<dim3(Bz), blk, 0, stream>>>(x, HX, zf);
  for (int f = 0; f < FUT; ++f) {
    __bf16* zc = zf + (size_t)(f & 1) * Bz * KTOT;
    __bf16* zn = zf + (size_t)((f & 1) ^ 1) * Bz * KTOT;
    k_fstep<<<dim3(DH / 64), blk, 0, stream>>>(zc, zn, WhT, bh);
    k_fout<<<dim3(DOUT / 64), blk, 0, stream>>>(zn, WoT, bo, pred, f);
  }
}